// Round 18
// baseline (48.552 us; speedup 1.0000x reference)
//
#include <hip/hip_runtime.h>

// LGCN on MI355X. N=1600, Fin=1433, GCN hidden=32, two LGConv (+8 ch each),
// out 7, row mask. zero_k + k1 (CSR/mask/weight-transpose/split-K GEMM with
// atomicAdd into h0) + k2 (S -> LG1 -> LG2+z -> F with 3 fence-free barriers).
// R17: conv1 lane=o (weights read once, 5 p's in-register; 2.8x fewer LDS instr);
// conv2 64-lane ci-split + shfl reduce (Wb in LDS); LG2 reuses LG1 topk via
// persistent T (TS=44 both phases) and only gathers the 8 c1 columns.

constexpr int NN   = 1600;
constexpr int FIN  = 1433;
constexpr int HGCN = 32;
constexpr int NBS  = 96;
constexpr float BN_EPS = 1e-3f;

constexpr int KS    = 16;
constexpr int CHUNK = 90;   // 16*90 = 1440 >= 1433
constexpr int BM    = 32;
constexpr int SXS   = 92;
constexpr int RB    = NN / BM;            // 50
constexpr int CSRB  = 400;                // csr blocks (4 rows each)
constexpr int K1B   = CSRB + 1 + RB * KS; // 1201
constexpr int GB    = 256;                // k2 grid (<= #CUs -> co-resident)
constexpr int NT    = 512;
constexpr int TS    = 44;                 // T row stride (mult of 4; banks tiled)
constexpr int ZBYTES = 225280;            // cntrel + h0 region

__device__ __forceinline__ void astore(float* p, float v) {
    __hip_atomic_store(p, v, __ATOMIC_RELAXED, __HIP_MEMORY_SCOPE_AGENT);
}
__device__ __forceinline__ void astorei(int* p, int v) {
    __hip_atomic_store(p, v, __ATOMIC_RELAXED, __HIP_MEMORY_SCOPE_AGENT);
}
__device__ __forceinline__ int aloadi(const int* p) {
    return __hip_atomic_load(p, __ATOMIC_RELAXED, __HIP_MEMORY_SCOPE_AGENT);
}

// ---------------- workspace zeroing ---------------------------------------------
__global__ __launch_bounds__(512) void zero_k(float4* __restrict__ p) {
    int i = blockIdx.x * 512 + threadIdx.x;
    if (i < ZBYTES / 16) p[i] = make_float4(0.f, 0.f, 0.f, 0.f);
}

// ---------------- per-block-slot grid barrier (no RMW, validated R14) ----------
__device__ __forceinline__ void gbar(int* cntrel, int phase) {
    int* cnt = cntrel + phase * GB;
    int* rel = cntrel + 896 + phase;
    __syncthreads();
    if (blockIdx.x == 0) {
        int s = threadIdx.x;
        if (s >= 1 && s < GB) {
            while (aloadi(&cnt[s]) == 0) __builtin_amdgcn_s_sleep(1);
        }
        __syncthreads();
        if (threadIdx.x == 0) astorei(rel, 1);
    } else {
        if (threadIdx.x == 0) {
            astorei(&cnt[blockIdx.x], 1);
            while (aloadi(rel) == 0) __builtin_amdgcn_s_sleep(1);
        }
    }
    __syncthreads();
}

// ================= K1 ===========================================================
__global__ __launch_bounds__(256) void k1(const float* __restrict__ x,
                                          const float* __restrict__ W0,
                                          const float* __restrict__ adj,
                                          const float* __restrict__ W1a,
                                          const float* __restrict__ W2a,
                                          int* __restrict__ deg,
                                          unsigned short* __restrict__ nbr,
                                          const unsigned char* __restrict__ mb,
                                          int* __restrict__ flag,
                                          float* __restrict__ wsT1,
                                          float* __restrict__ wsT2,
                                          float* __restrict__ h0) {
    __shared__ float sx[BM][SXS];
    __shared__ float sw[CHUNK * HGCN];
    int b = blockIdx.x, t = threadIdx.x;

    if (b < CSRB) {                        // ---- CSR build: 4 waves, 1 row each
        int lane = t & 63;
        int row  = b * 4 + (t >> 6);
        const float*  ar  = adj + (size_t)row * NN;
        const float4* ar4 = (const float4*)ar;
        unsigned short* nb = nbr + (size_t)row * NBS;
        int cnt = 0;
        #pragma unroll
        for (int it = 0; it < 6; ++it) {   // 6*256 = 1536 elements
            float4 v = ar4[it * 64 + lane];
            int base = it * 256 + 4 * lane;
            #pragma unroll
            for (int c = 0; c < 4; ++c) {
                float vc = (c == 0) ? v.x : (c == 1) ? v.y : (c == 2) ? v.z : v.w;
                bool p = (vc != 0.0f);
                unsigned long long m = __ballot(p);
                if (p) {
                    int off = cnt + __popcll(m & ((1ull << lane) - 1ull));
                    if (off < NBS) nb[off] = (unsigned short)(base + c);
                }
                cnt += __popcll(m);
            }
        }
        {                                  // tail 64
            float v = ar[1536 + lane];
            bool p = (v != 0.0f);
            unsigned long long m = __ballot(p);
            if (p) {
                int off = cnt + __popcll(m & ((1ull << lane) - 1ull));
                if (off < NBS) nb[off] = (unsigned short)(1536 + lane);
            }
            cnt += __popcll(m);
        }
        if (lane == 0) deg[row] = cnt < NBS ? cnt : NBS;
        return;
    }

    if (b == CSRB) {                       // ---- mask detect + weight transpose
        if (t < 64) {
            int lane = t;
            bool odd = false, flt = false;
            for (int i = lane; i < NN; i += 64) {
                unsigned char v = mb[i];
                if (v) {
                    int r = i & 3;
                    if (r != 0) odd = true;
                    if (r >= 2 && (v == 0x3F || v == 0x80)) flt = true;  // 1.0f
                }
            }
            unsigned long long mo = __ballot(odd);
            unsigned long long mf = __ballot(flt);
            if (lane == 0) *flag = mf ? 2 : (mo ? 1 : 0);  // 2=f32,1=u8,0=i32
        }
        // W1a [5][32][20] -> wsT1 f4[(kw*8+q)*20+o] = {W1a[kw][4q+j][o]}
        for (int f = t; f < 800; f += 256) {
            int kw = f / 160, r = f - kw * 160, q = r / 20, o = r - q * 20;
            const float* wsrc = W1a + kw * 640 + 4 * q * 20 + o;
            float4 v;
            v.x = wsrc[0]; v.y = wsrc[20]; v.z = wsrc[40]; v.w = wsrc[60];
            ((float4*)wsT1)[f] = v;
        }
        // W2a [5][40][24] -> wsT2 f4[(kw*10+q)*24+o] = {W2a[kw][4q+j][o]}
        for (int f = t; f < 1200; f += 256) {
            int kw = f / 240, r = f - kw * 240, q = r / 24, o = r - q * 24;
            const float* wsrc = W2a + kw * 960 + 4 * q * 24 + o;
            float4 v;
            v.x = wsrc[0]; v.y = wsrc[24]; v.z = wsrc[48]; v.w = wsrc[72];
            ((float4*)wsT2)[f] = v;
        }
        return;
    }

    // ---- GEMM tile: atomicAdd partial x@W0 into h0 (h0 pre-zeroed by zero_k)
    int tile = b - (CSRB + 1);
    int rb   = tile % RB;
    int ks   = tile / RB;
    int lane = t & 31;
    int row0 = rb * BM;
    int k0   = ks * CHUNK;
    int vk   = FIN - k0; if (vk > CHUNK) vk = CHUNK;

    {
        int g = t >> 5;
        #pragma unroll
        for (int j = 0; j < 4; ++j) {
            int r = g + 8 * j;
            const float* xr = x + (size_t)(row0 + r) * FIN + k0;
            #pragma unroll
            for (int m = 0; m < 3; ++m) {
                int k = lane + 32 * m;
                if (k < CHUNK) sx[r][k] = (k < vk) ? xr[k] : 0.0f;
            }
        }
    }
    {
        const float4* w4  = (const float4*)(W0 + (size_t)k0 * HGCN);
        float4*       sw4 = (float4*)sw;
        int vf4 = vk * 8;
        for (int i = t; i < CHUNK * 8; i += 256)
            sw4[i] = (i < vf4) ? w4[i] : make_float4(0.f, 0.f, 0.f, 0.f);
    }
    __syncthreads();

    int col = lane;
    int rq  = t >> 5;
    float acc0 = 0.f, acc1 = 0.f, acc2 = 0.f, acc3 = 0.f;
    #pragma unroll 4
    for (int kk = 0; kk < 88; kk += 4) {
        float4 a0 = *(const float4*)&sx[rq     ][kk];
        float4 a1 = *(const float4*)&sx[rq +  8][kk];
        float4 a2 = *(const float4*)&sx[rq + 16][kk];
        float4 a3 = *(const float4*)&sx[rq + 24][kk];
        float w0v = sw[(kk + 0) * HGCN + col];
        float w1v = sw[(kk + 1) * HGCN + col];
        float w2v = sw[(kk + 2) * HGCN + col];
        float w3v = sw[(kk + 3) * HGCN + col];
        acc0 += a0.x * w0v + a0.y * w1v + a0.z * w2v + a0.w * w3v;
        acc1 += a1.x * w0v + a1.y * w1v + a1.z * w2v + a1.w * w3v;
        acc2 += a2.x * w0v + a2.y * w1v + a2.z * w2v + a2.w * w3v;
        acc3 += a3.x * w0v + a3.y * w1v + a3.z * w2v + a3.w * w3v;
    }
    #pragma unroll
    for (int kk = 88; kk < CHUNK; ++kk) {
        float wv = sw[kk * HGCN + col];
        acc0 += sx[rq     ][kk] * wv;
        acc1 += sx[rq +  8][kk] * wv;
        acc2 += sx[rq + 16][kk] * wv;
        acc3 += sx[rq + 24][kk] * wv;
    }

    atomicAdd(&h0[(row0 + rq     ) * HGCN + col], acc0);
    atomicAdd(&h0[(row0 + rq +  8) * HGCN + col], acc1);
    atomicAdd(&h0[(row0 + rq + 16) * HGCN + col], acc2);
    atomicAdd(&h0[(row0 + rq + 24) * HGCN + col], acc3);
}

// ================= K2 phases ====================================================
// Wave-private lgconv, T row stride TS=44 for BOTH phases (persists LG1->LG2).
// conv1: lane = o, 5 p-accumulators in-register, weights read exactly once.
// conv2: 64 lanes (o = lane&7, grp = lane>>3 splits ci), shfl_xor reduce.
template<int F, int MID, bool WRITEZ>
__device__ __forceinline__ void lgconv_phase(int b, int wave, int lane,
        const int* __restrict__ deg, const unsigned short* __restrict__ nbr,
        const float* sWt, const float* sWb,
        const float* __restrict__ g, const float* __restrict__ bb,
        const float* __restrict__ mm, const float* __restrict__ vv,
        const float* __restrict__ h32, const float* __restrict__ c1in,
        const float* __restrict__ Wout,
        float* __restrict__ outbuf, float* T, float* C1) {
    int row = b + 256 * wave;               // striped (same mapping both phases)
    if (row >= NN) return;
    int d = deg[row];
    const unsigned short* nb = nbr + (size_t)row * NBS;

    // ---- topk: LG1 gathers h32 (lanes 0..31); LG2 only c1 (lanes 32..39) ----
    bool tk = (F == 32) ? (lane < 32) : (lane >= 32 && lane < 40);
    if (tk) {
        float t0=0.f,t1=0.f,t2=0.f,t3=0.f,t4=0.f,t5=0.f,t6=0.f,t7=0.f;
        #define BUBBLE(val_) { float val=val_, c;                       \
            c = t0; t0 = fmaxf(c, val); val = fminf(c, val);            \
            c = t1; t1 = fmaxf(c, val); val = fminf(c, val);            \
            c = t2; t2 = fmaxf(c, val); val = fminf(c, val);            \
            c = t3; t3 = fmaxf(c, val); val = fminf(c, val);            \
            c = t4; t4 = fmaxf(c, val); val = fminf(c, val);            \
            c = t5; t5 = fmaxf(c, val); val = fminf(c, val);            \
            c = t6; t6 = fmaxf(c, val); val = fminf(c, val);            \
            c = t7; t7 = fmaxf(c, val); val = fminf(c, val); }
        #define LDV(n_) ((F == 32) ? h32[(n_) * HGCN + lane]            \
                                   : c1in[(n_) * 8 + (lane - 32)])
        int it = 0;
        for (; it + 8 <= d; it += 8) {
            float v[8];
            #pragma unroll
            for (int j = 0; j < 8; ++j) v[j] = LDV((int)nb[it + j]);
            #pragma unroll
            for (int j = 0; j < 8; ++j) BUBBLE(v[j]);
        }
        for (; it < d; ++it) BUBBLE(LDV((int)nb[it]));
        T[0*TS+lane] = LDV(row);            // own feature first
        T[1*TS+lane] = t0; T[2*TS+lane] = t1; T[3*TS+lane] = t2; T[4*TS+lane] = t3;
        T[5*TS+lane] = t4; T[6*TS+lane] = t5; T[7*TS+lane] = t6; T[8*TS+lane] = t7;
        #undef LDV
        #undef BUBBLE
    }

    // ---- conv1: lane = o; weights read once; 5 p's in-register ----
    if (lane < MID) {
        int o = lane;
        float4 a0 = {0,0,0,0}, a1 = {0,0,0,0}, a2 = {0,0,0,0},
               a3 = {0,0,0,0}, a4 = {0,0,0,0};
        for (int q = 0; q < F / 4; ++q) {
            float4 tq[9];
            #pragma unroll
            for (int pos = 0; pos < 9; ++pos)
                tq[pos] = *(const float4*)&T[pos * TS + 4 * q];
            #pragma unroll
            for (int kw = 0; kw < 5; ++kw) {
                float4 wv = ((const float4*)sWt)[(kw * (F / 4) + q) * MID + o];
                #define ACC(ap_, pos_) { float4 tv = tq[pos_];          \
                    ap_.x += tv.x * wv.x; ap_.y += tv.y * wv.y;         \
                    ap_.z += tv.z * wv.z; ap_.w += tv.w * wv.w; }
                ACC(a0, kw + 0) ACC(a1, kw + 1) ACC(a2, kw + 2)
                ACC(a3, kw + 3) ACC(a4, kw + 4)
                #undef ACC
            }
        }
        C1[0 * MID + o] = (a0.x + a0.y) + (a0.z + a0.w);
        C1[1 * MID + o] = (a1.x + a1.y) + (a1.z + a1.w);
        C1[2 * MID + o] = (a2.x + a2.y) + (a2.z + a2.w);
        C1[3 * MID + o] = (a3.x + a3.y) + (a3.z + a3.w);
        C1[4 * MID + o] = (a4.x + a4.y) + (a4.z + a4.w);
    }

    // ---- conv2 + BN: 64 lanes, grp splits the 5*MID ci-terms, shfl reduce ----
    {
        int grp = lane >> 3, o = lane & 7;
        float acc = 0.f;
        for (int idx = grp; idx < 5 * MID; idx += 8)
            acc += C1[idx] * sWb[idx * 8 + o];
        acc += __shfl_xor(acc, 8);
        acc += __shfl_xor(acc, 16);
        acc += __shfl_xor(acc, 32);
        float y = g[o] * (acc - mm[o]) * rsqrtf(vv[o] + BN_EPS) + bb[o];

        if (!WRITEZ) {
            if (lane < 8) astore(&outbuf[row * 8 + lane], y);
        } else {
            float yv[8];
            #pragma unroll
            for (int j = 0; j < 8; ++j) yv[j] = __shfl(y, j);  // lanes 0..7 hold o=0..7
            if (lane < 8) {
                float z = 0.f;
                if (lane < 7) {
                    const float4* tf = (const float4*)T;       // row 0 = h_ext[0:40]
                    #pragma unroll
                    for (int k4 = 0; k4 < 10; ++k4) {
                        float4 tv = tf[k4];
                        z += tv.x * Wout[(4 * k4 + 0) * 7 + lane]
                           + tv.y * Wout[(4 * k4 + 1) * 7 + lane]
                           + tv.z * Wout[(4 * k4 + 2) * 7 + lane]
                           + tv.w * Wout[(4 * k4 + 3) * 7 + lane];
                    }
                    #pragma unroll
                    for (int j = 0; j < 8; ++j)
                        z += yv[j] * Wout[(40 + j) * 7 + lane];
                }
                astore(&outbuf[row * 8 + lane], z);            // col 7 = 0
            }
        }
    }
}

__global__ __launch_bounds__(NT) void k2(
        const int* __restrict__ deg, const unsigned short* __restrict__ nbr,
        const float* __restrict__ h0,
        float* __restrict__ h32, float* __restrict__ c1, float* __restrict__ zbuf,
        const float* __restrict__ wsT1, const float* __restrict__ wsT2,
        const float* __restrict__ W1b,
        const float* __restrict__ g1, const float* __restrict__ b1,
        const float* __restrict__ m1, const float* __restrict__ v1,
        const float* __restrict__ W2b,
        const float* __restrict__ g2, const float* __restrict__ b2,
        const float* __restrict__ m2, const float* __restrict__ v2,
        const float* __restrict__ Wout, const void* __restrict__ mask,
        const int* __restrict__ flag, int* __restrict__ cntrel,
        float* __restrict__ out) {
    __shared__ float sWt1[3200];            // f4[5*8*20]
    __shared__ float sWt2[4800];            // f4[5*10*24]
    __shared__ float sWb1[800];             // W1b flat
    __shared__ float sWb2[960];             // W2b flat
    __shared__ float T   [8][9 * TS + 4];   // persists LG1 -> LG2
    __shared__ float C1s [8][120];
    int t = threadIdx.x, b = blockIdx.x;
    int wave = t >> 6, lane = t & 63;

    // stage all weight sets once (consumed after gbar 0)
    {
        const float4* s1 = (const float4*)wsT1;
        const float4* s2 = (const float4*)wsT2;
        const float4* s3 = (const float4*)W1b;
        const float4* s4 = (const float4*)W2b;
        float4* d1 = (float4*)sWt1;
        float4* d2 = (float4*)sWt2;
        float4* d3 = (float4*)sWb1;
        float4* d4 = (float4*)sWb2;
        for (int i = t; i < 800;  i += NT) d1[i] = s1[i];
        for (int i = t; i < 1200; i += NT) d2[i] = s2[i];
        for (int i = t; i < 200;  i += NT) d3[i] = s3[i];
        for (int i = t; i < 240;  i += NT) d4[i] = s4[i];
    }

    // ---- phase S: h32 = adj @ h0 (full wave per row, 2-half neighbor split)
    {
        int row = b + 256 * wave;
        if (row < NN) {
            int f = lane & 31, half = lane >> 5;
            int d = deg[row];
            const unsigned short* nb = nbr + (size_t)row * NBS;
            float acc = 0.f;
            int it = half;
            for (; it + 16 <= d; it += 16) {       // 8-deep per half
                float v[8];
                #pragma unroll
                for (int j = 0; j < 8; ++j) v[j] = h0[(int)nb[it + 2 * j] * HGCN + f];
                #pragma unroll
                for (int j = 0; j < 8; ++j) acc += v[j];
            }
            for (; it < d; it += 2) acc += h0[(int)nb[it] * HGCN + f];
            acc += __shfl_xor(acc, 32);
            if (half == 0) astore(&h32[row * HGCN + f], acc);
        }
    }
    gbar(cntrel, 0);

    lgconv_phase<32, 20, false>(b, wave, lane, deg, nbr, sWt1, sWb1,
                                g1, b1, m1, v1, h32, nullptr, Wout, c1,
                                T[wave], C1s[wave]);
    gbar(cntrel, 1);

    lgconv_phase<40, 24, true>(b, wave, lane, deg, nbr, sWt2, sWb2,
                               g2, b2, m2, v2, h32, c1, Wout, zbuf,
                               T[wave], C1s[wave]);
    gbar(cntrel, 2);

    // ---- phase F: out[row] = mask ? sum_{n in nbr(row)} z[n] : 0
    {
        int row = b + 256 * wave;
        if (row < NN) {
            int d = deg[row];
            const unsigned short* nb = nbr + (size_t)row * NBS;
            int ng = lane >> 3, c = lane & 7;
            float acc = 0.f;
            for (int it = ng; it < d; it += 8)
                acc += zbuf[(int)nb[it] * 8 + c];
            acc += __shfl_xor(acc, 8);
            acc += __shfl_xor(acc, 16);
            acc += __shfl_xor(acc, 32);
            if (lane < 7) {
                int fl = *flag;
                bool mk;
                if (fl == 2)      mk = ((const float*)mask)[row] != 0.0f;
                else if (fl == 1) mk = ((const unsigned char*)mask)[row] != 0;
                else              mk = ((const int*)mask)[row] != 0;
                out[row * 7 + lane] = mk ? acc : 0.0f;
            }
        }
    }
}

extern "C" void kernel_launch(void* const* d_in, const int* in_sizes, int n_in,
                              void* d_out, int out_size, void* d_ws, size_t ws_size,
                              hipStream_t stream) {
    const float* x    = (const float*)d_in[0];
    const float* adj  = (const float*)d_in[1];
    const float* W0   = (const float*)d_in[2];
    const float* W1a  = (const float*)d_in[3];
    const float* W1b  = (const float*)d_in[4];
    const float* W2a  = (const float*)d_in[5];
    const float* W2b  = (const float*)d_in[6];
    const float* Wout = (const float*)d_in[7];
    const float* g1 = (const float*)d_in[8];
    const float* b1 = (const float*)d_in[9];
    const float* m1 = (const float*)d_in[10];
    const float* v1 = (const float*)d_in[11];
    const float* g2 = (const float*)d_in[12];
    const float* b2 = (const float*)d_in[13];
    const float* m2 = (const float*)d_in[14];
    const float* v2 = (const float*)d_in[15];
    const void*  mask = d_in[16];

    char* ws = (char*)d_ws;
    int*            cntrel = (int*)(ws + 0);        // 3*256 slots + rel@896 (4KB)
    float*          h0     = (float*)(ws + 20480);  // 204800 B [zeroed 0..225280]
    int*            flag   = (int*)(ws + 225280);   // 512 B reserved
    int*            deg    = (int*)(ws + 225792);   // 6400 B
    unsigned short* nbr    = (unsigned short*)(ws + 232192); // 307200 B
    float*          h32    = (float*)(ws + 539392); // 204800 B
    float*          c1     = (float*)(ws + 744192); // 51200 B
    float*          zbuf   = (float*)(ws + 795392); // 51200 B
    float*          wsT1   = (float*)(ws + 846592); // 12800 B
    float*          wsT2   = (float*)(ws + 859392); // 19200 B

    float* out = (float*)d_out;

    zero_k<<<(ZBYTES / 16 + 511) / 512, 512, 0, stream>>>((float4*)ws);
    k1<<<K1B, 256, 0, stream>>>(x, W0, adj, W1a, W2a, deg, nbr,
                                (const unsigned char*)mask, flag, wsT1, wsT2, h0);
    k2<<<GB, NT, 0, stream>>>(deg, nbr, h0, h32, c1, zbuf, wsT1, wsT2,
                              W1b, g1, b1, m1, v1,
                              W2b, g2, b2, m2, v2,
                              Wout, mask, flag, cntrel, out);
}

// Round 19
// 45.715 us; speedup vs baseline: 1.0621x; 1.0621x over previous
//
#include <hip/hip_runtime.h>

// LGCN on MI355X. N=1600, Fin=1433, GCN hidden=32, two LGConv (+8 ch each),
// out 7, row mask. TWO launches:
// k1: CSR build + mask detect + weight transpose + cntrel zero + split-K GEMM
//     (plain coalesced stores to hp[ks][row][col] -- NO atomics).
// k2: R (reduce hp->h0) -> S -> LG1 -> LG2+z -> F with 4 fence-free barriers.
// Cross-block writes in k2: agent-scope relaxed atomic stores (sc1, MALL).
// Reads: normal cached loads (stale-L2 lines can only hold identical values).
// R19: atomicAdd accumulation removed (819K RMWs ~ 10us tail); zero_k removed
// (h0 fully overwritten by R; cntrel zeroed inside k1); rel flag x32 lines.

constexpr int NN   = 1600;
constexpr int FIN  = 1433;
constexpr int HGCN = 32;
constexpr int NBS  = 96;
constexpr float BN_EPS = 1e-3f;

constexpr int KS    = 16;
constexpr int CHUNK = 90;   // 16*90 = 1440 >= 1433
constexpr int BM    = 32;
constexpr int SXS   = 92;
constexpr int RB    = NN / BM;            // 50
constexpr int CSRB  = 400;                // csr blocks (4 rows each)
constexpr int K1B   = CSRB + 1 + RB * KS; // 1201
constexpr int GB    = 256;                // k2 grid (<= #CUs -> co-resident)
constexpr int NT    = 512;
constexpr int TS    = 44;                 // T row stride (banks tiled)

__device__ __forceinline__ void astore(float* p, float v) {
    __hip_atomic_store(p, v, __ATOMIC_RELAXED, __HIP_MEMORY_SCOPE_AGENT);
}
__device__ __forceinline__ void astorei(int* p, int v) {
    __hip_atomic_store(p, v, __ATOMIC_RELAXED, __HIP_MEMORY_SCOPE_AGENT);
}
__device__ __forceinline__ int aloadi(const int* p) {
    return __hip_atomic_load(p, __ATOMIC_RELAXED, __HIP_MEMORY_SCOPE_AGENT);
}

// ---------------- per-block-slot grid barrier, 32-line replicated release ------
// cnt: 4 phases x 256 slots. rel: copy c for phase p at [1024 + c*32 + p]
// (copies stride 128B lines). Zeroed by k1 block CSRB (k1 never reads cntrel).
__device__ __forceinline__ void gbar(int* cntrel, int phase) {
    int* cnt = cntrel + phase * GB;
    __syncthreads();
    if (blockIdx.x == 0) {
        int s = threadIdx.x;
        if (s >= 1 && s < GB) {
            while (aloadi(&cnt[s]) == 0) __builtin_amdgcn_s_sleep(1);
        }
        __syncthreads();
        if (threadIdx.x < 32)
            astorei(&cntrel[1024 + threadIdx.x * 32 + phase], 1);
    } else {
        if (threadIdx.x == 0) {
            astorei(&cnt[blockIdx.x], 1);
            while (aloadi(&cntrel[1024 + (blockIdx.x & 31) * 32 + phase]) == 0)
                __builtin_amdgcn_s_sleep(1);
        }
    }
    __syncthreads();
}

// ================= K1 ===========================================================
__global__ __launch_bounds__(256) void k1(const float* __restrict__ x,
                                          const float* __restrict__ W0,
                                          const float* __restrict__ adj,
                                          const float* __restrict__ W1a,
                                          const float* __restrict__ W2a,
                                          int* __restrict__ deg,
                                          unsigned short* __restrict__ nbr,
                                          const unsigned char* __restrict__ mb,
                                          int* __restrict__ flag,
                                          float* __restrict__ wsT1,
                                          float* __restrict__ wsT2,
                                          int* __restrict__ cntrel,
                                          float* __restrict__ hp) {
    __shared__ float sx[BM][SXS];
    __shared__ float sw[CHUNK * HGCN];
    int b = blockIdx.x, t = threadIdx.x;

    if (b < CSRB) {                        // ---- CSR build: 4 waves, 1 row each
        int lane = t & 63;
        int row  = b * 4 + (t >> 6);
        const float*  ar  = adj + (size_t)row * NN;
        const float4* ar4 = (const float4*)ar;
        unsigned short* nb = nbr + (size_t)row * NBS;
        int cnt = 0;
        #pragma unroll
        for (int it = 0; it < 6; ++it) {   // 6*256 = 1536 elements
            float4 v = ar4[it * 64 + lane];
            int base = it * 256 + 4 * lane;
            #pragma unroll
            for (int c = 0; c < 4; ++c) {
                float vc = (c == 0) ? v.x : (c == 1) ? v.y : (c == 2) ? v.z : v.w;
                bool p = (vc != 0.0f);
                unsigned long long m = __ballot(p);
                if (p) {
                    int off = cnt + __popcll(m & ((1ull << lane) - 1ull));
                    if (off < NBS) nb[off] = (unsigned short)(base + c);
                }
                cnt += __popcll(m);
            }
        }
        {                                  // tail 64
            float v = ar[1536 + lane];
            bool p = (v != 0.0f);
            unsigned long long m = __ballot(p);
            if (p) {
                int off = cnt + __popcll(m & ((1ull << lane) - 1ull));
                if (off < NBS) nb[off] = (unsigned short)(1536 + lane);
            }
            cnt += __popcll(m);
        }
        if (lane == 0) deg[row] = cnt < NBS ? cnt : NBS;
        return;
    }

    if (b == CSRB) {           // ---- cntrel zero + mask detect + weight transpose
        for (int i = t; i < 2048; i += 256) cntrel[i] = 0;
        if (t < 64) {
            int lane = t;
            bool odd = false, flt = false;
            for (int i = lane; i < NN; i += 64) {
                unsigned char v = mb[i];
                if (v) {
                    int r = i & 3;
                    if (r != 0) odd = true;
                    if (r >= 2 && (v == 0x3F || v == 0x80)) flt = true;  // 1.0f
                }
            }
            unsigned long long mo = __ballot(odd);
            unsigned long long mf = __ballot(flt);
            if (lane == 0) *flag = mf ? 2 : (mo ? 1 : 0);  // 2=f32,1=u8,0=i32
        }
        // W1a [5][32][20] -> wsT1 f4[(kw*8+q)*20+o] = {W1a[kw][4q+j][o]}
        for (int f = t; f < 800; f += 256) {
            int kw = f / 160, r = f - kw * 160, q = r / 20, o = r - q * 20;
            const float* wsrc = W1a + kw * 640 + 4 * q * 20 + o;
            float4 v;
            v.x = wsrc[0]; v.y = wsrc[20]; v.z = wsrc[40]; v.w = wsrc[60];
            ((float4*)wsT1)[f] = v;
        }
        // W2a [5][40][24] -> wsT2 f4[(kw*10+q)*24+o] = {W2a[kw][4q+j][o]}
        for (int f = t; f < 1200; f += 256) {
            int kw = f / 240, r = f - kw * 240, q = r / 24, o = r - q * 24;
            const float* wsrc = W2a + kw * 960 + 4 * q * 24 + o;
            float4 v;
            v.x = wsrc[0]; v.y = wsrc[24]; v.z = wsrc[48]; v.w = wsrc[72];
            ((float4*)wsT2)[f] = v;
        }
        return;
    }

    // ---- GEMM tile: plain coalesced stores of partials to hp[ks][row][col]
    int tile = b - (CSRB + 1);
    int rb   = tile % RB;
    int ks   = tile / RB;
    int lane = t & 31;
    int row0 = rb * BM;
    int k0   = ks * CHUNK;
    int vk   = FIN - k0; if (vk > CHUNK) vk = CHUNK;

    {
        int g = t >> 5;
        #pragma unroll
        for (int j = 0; j < 4; ++j) {
            int r = g + 8 * j;
            const float* xr = x + (size_t)(row0 + r) * FIN + k0;
            #pragma unroll
            for (int m = 0; m < 3; ++m) {
                int k = lane + 32 * m;
                if (k < CHUNK) sx[r][k] = (k < vk) ? xr[k] : 0.0f;
            }
        }
    }
    {
        const float4* w4  = (const float4*)(W0 + (size_t)k0 * HGCN);
        float4*       sw4 = (float4*)sw;
        int vf4 = vk * 8;
        for (int i = t; i < CHUNK * 8; i += 256)
            sw4[i] = (i < vf4) ? w4[i] : make_float4(0.f, 0.f, 0.f, 0.f);
    }
    __syncthreads();

    int col = lane;
    int rq  = t >> 5;
    float acc0 = 0.f, acc1 = 0.f, acc2 = 0.f, acc3 = 0.f;
    #pragma unroll 4
    for (int kk = 0; kk < 88; kk += 4) {
        float4 a0 = *(const float4*)&sx[rq     ][kk];
        float4 a1 = *(const float4*)&sx[rq +  8][kk];
        float4 a2 = *(const float4*)&sx[rq + 16][kk];
        float4 a3 = *(const float4*)&sx[rq + 24][kk];
        float w0v = sw[(kk + 0) * HGCN + col];
        float w1v = sw[(kk + 1) * HGCN + col];
        float w2v = sw[(kk + 2) * HGCN + col];
        float w3v = sw[(kk + 3) * HGCN + col];
        acc0 += a0.x * w0v + a0.y * w1v + a0.z * w2v + a0.w * w3v;
        acc1 += a1.x * w0v + a1.y * w1v + a1.z * w2v + a1.w * w3v;
        acc2 += a2.x * w0v + a2.y * w1v + a2.z * w2v + a2.w * w3v;
        acc3 += a3.x * w0v + a3.y * w1v + a3.z * w2v + a3.w * w3v;
    }
    #pragma unroll
    for (int kk = 88; kk < CHUNK; ++kk) {
        float wv = sw[kk * HGCN + col];
        acc0 += sx[rq     ][kk] * wv;
        acc1 += sx[rq +  8][kk] * wv;
        acc2 += sx[rq + 16][kk] * wv;
        acc3 += sx[rq + 24][kk] * wv;
    }

    float* o = hp + (size_t)ks * NN * HGCN + (size_t)(row0 + rq) * HGCN + col;
    o[0 * 8 * HGCN] = acc0;
    o[1 * 8 * HGCN] = acc1;
    o[2 * 8 * HGCN] = acc2;
    o[3 * 8 * HGCN] = acc3;
}

// ================= K2 phases ====================================================
// Wave-private lgconv, T row stride TS=44 both phases (persists LG1->LG2).
// conv1: lane = o, 5 p-accumulators in-register, weights read exactly once.
// conv2: 64 lanes (o = lane&7, grp = lane>>3 splits ci), shfl_xor reduce.
template<int F, int MID, bool WRITEZ>
__device__ __forceinline__ void lgconv_phase(int b, int wave, int lane,
        const int* __restrict__ deg, const unsigned short* __restrict__ nbr,
        const float* sWt, const float* sWb,
        const float* __restrict__ g, const float* __restrict__ bb,
        const float* __restrict__ mm, const float* __restrict__ vv,
        const float* __restrict__ h32, const float* __restrict__ c1in,
        const float* __restrict__ Wout,
        float* __restrict__ outbuf, float* T, float* C1) {
    int row = b + 256 * wave;               // striped (same mapping both phases)
    if (row >= NN) return;
    int d = deg[row];
    const unsigned short* nb = nbr + (size_t)row * NBS;

    // ---- topk: LG1 gathers h32 (lanes 0..31); LG2 only c1 (lanes 32..39) ----
    bool tk = (F == 32) ? (lane < 32) : (lane >= 32 && lane < 40);
    if (tk) {
        float t0=0.f,t1=0.f,t2=0.f,t3=0.f,t4=0.f,t5=0.f,t6=0.f,t7=0.f;
        #define BUBBLE(val_) { float val=val_, c;                       \
            c = t0; t0 = fmaxf(c, val); val = fminf(c, val);            \
            c = t1; t1 = fmaxf(c, val); val = fminf(c, val);            \
            c = t2; t2 = fmaxf(c, val); val = fminf(c, val);            \
            c = t3; t3 = fmaxf(c, val); val = fminf(c, val);            \
            c = t4; t4 = fmaxf(c, val); val = fminf(c, val);            \
            c = t5; t5 = fmaxf(c, val); val = fminf(c, val);            \
            c = t6; t6 = fmaxf(c, val); val = fminf(c, val);            \
            c = t7; t7 = fmaxf(c, val); val = fminf(c, val); }
        #define LDV(n_) ((F == 32) ? h32[(n_) * HGCN + lane]            \
                                   : c1in[(n_) * 8 + (lane - 32)])
        int it = 0;
        for (; it + 8 <= d; it += 8) {
            float v[8];
            #pragma unroll
            for (int j = 0; j < 8; ++j) v[j] = LDV((int)nb[it + j]);
            #pragma unroll
            for (int j = 0; j < 8; ++j) BUBBLE(v[j]);
        }
        for (; it < d; ++it) BUBBLE(LDV((int)nb[it]));
        T[0*TS+lane] = LDV(row);            // own feature first
        T[1*TS+lane] = t0; T[2*TS+lane] = t1; T[3*TS+lane] = t2; T[4*TS+lane] = t3;
        T[5*TS+lane] = t4; T[6*TS+lane] = t5; T[7*TS+lane] = t6; T[8*TS+lane] = t7;
        #undef LDV
        #undef BUBBLE
    }

    // ---- conv1: lane = o; weights read once; 5 p's in-register ----
    if (lane < MID) {
        int o = lane;
        float4 a0 = {0,0,0,0}, a1 = {0,0,0,0}, a2 = {0,0,0,0},
               a3 = {0,0,0,0}, a4 = {0,0,0,0};
        for (int q = 0; q < F / 4; ++q) {
            float4 tq[9];
            #pragma unroll
            for (int pos = 0; pos < 9; ++pos)
                tq[pos] = *(const float4*)&T[pos * TS + 4 * q];
            #pragma unroll
            for (int kw = 0; kw < 5; ++kw) {
                float4 wv = ((const float4*)sWt)[(kw * (F / 4) + q) * MID + o];
                #define ACC(ap_, pos_) { float4 tv = tq[pos_];          \
                    ap_.x += tv.x * wv.x; ap_.y += tv.y * wv.y;         \
                    ap_.z += tv.z * wv.z; ap_.w += tv.w * wv.w; }
                ACC(a0, kw + 0) ACC(a1, kw + 1) ACC(a2, kw + 2)
                ACC(a3, kw + 3) ACC(a4, kw + 4)
                #undef ACC
            }
        }
        C1[0 * MID + o] = (a0.x + a0.y) + (a0.z + a0.w);
        C1[1 * MID + o] = (a1.x + a1.y) + (a1.z + a1.w);
        C1[2 * MID + o] = (a2.x + a2.y) + (a2.z + a2.w);
        C1[3 * MID + o] = (a3.x + a3.y) + (a3.z + a3.w);
        C1[4 * MID + o] = (a4.x + a4.y) + (a4.z + a4.w);
    }

    // ---- conv2 + BN: 64 lanes, grp splits the 5*MID ci-terms, shfl reduce ----
    {
        int grp = lane >> 3, o = lane & 7;
        float acc = 0.f;
        for (int idx = grp; idx < 5 * MID; idx += 8)
            acc += C1[idx] * sWb[idx * 8 + o];
        acc += __shfl_xor(acc, 8);
        acc += __shfl_xor(acc, 16);
        acc += __shfl_xor(acc, 32);
        float y = g[o] * (acc - mm[o]) * rsqrtf(vv[o] + BN_EPS) + bb[o];

        if (!WRITEZ) {
            if (lane < 8) astore(&outbuf[row * 8 + lane], y);
        } else {
            float yv[8];
            #pragma unroll
            for (int j = 0; j < 8; ++j) yv[j] = __shfl(y, j);  // lanes 0..7: o=0..7
            if (lane < 8) {
                float z = 0.f;
                if (lane < 7) {
                    const float4* tf = (const float4*)T;       // row 0 = h_ext[0:40]
                    #pragma unroll
                    for (int k4 = 0; k4 < 10; ++k4) {
                        float4 tv = tf[k4];
                        z += tv.x * Wout[(4 * k4 + 0) * 7 + lane]
                           + tv.y * Wout[(4 * k4 + 1) * 7 + lane]
                           + tv.z * Wout[(4 * k4 + 2) * 7 + lane]
                           + tv.w * Wout[(4 * k4 + 3) * 7 + lane];
                    }
                    #pragma unroll
                    for (int j = 0; j < 8; ++j)
                        z += yv[j] * Wout[(40 + j) * 7 + lane];
                }
                astore(&outbuf[row * 8 + lane], z);            // col 7 = 0
            }
        }
    }
}

__global__ __launch_bounds__(NT) void k2(
        const int* __restrict__ deg, const unsigned short* __restrict__ nbr,
        const float* __restrict__ hp, float* __restrict__ h0,
        float* __restrict__ h32, float* __restrict__ c1, float* __restrict__ zbuf,
        const float* __restrict__ wsT1, const float* __restrict__ wsT2,
        const float* __restrict__ W1b,
        const float* __restrict__ g1, const float* __restrict__ b1,
        const float* __restrict__ m1, const float* __restrict__ v1,
        const float* __restrict__ W2b,
        const float* __restrict__ g2, const float* __restrict__ b2,
        const float* __restrict__ m2, const float* __restrict__ v2,
        const float* __restrict__ Wout, const void* __restrict__ mask,
        const int* __restrict__ flag, int* __restrict__ cntrel,
        float* __restrict__ out) {
    __shared__ float sWt1[3200];            // f4[5*8*20]
    __shared__ float sWt2[4800];            // f4[5*10*24]
    __shared__ float sWb1[800];             // W1b flat
    __shared__ float sWb2[960];             // W2b flat
    __shared__ float T   [8][9 * TS + 4];   // persists LG1 -> LG2
    __shared__ float C1s [8][120];
    int t = threadIdx.x, b = blockIdx.x;
    int wave = t >> 6, lane = t & 63;

    // stage all weight sets once (consumed after gbar 1)
    {
        const float4* s1 = (const float4*)wsT1;
        const float4* s2 = (const float4*)wsT2;
        const float4* s3 = (const float4*)W1b;
        const float4* s4 = (const float4*)W2b;
        float4* d1 = (float4*)sWt1;
        float4* d2 = (float4*)sWt2;
        float4* d3 = (float4*)sWb1;
        float4* d4 = (float4*)sWb2;
        for (int i = t; i < 800;  i += NT) d1[i] = s1[i];
        for (int i = t; i < 1200; i += NT) d2[i] = s2[i];
        for (int i = t; i < 200;  i += NT) d3[i] = s3[i];
        for (int i = t; i < 240;  i += NT) d4[i] = s4[i];
    }

    // ---- phase R: h0 = sum over split-K partials hp[ks][e] (coalesced, det.)
    {
        if (t < 200) {
            int e = b * 200 + t;            // 256*200 = 51200 elements
            float s = 0.f;
            #pragma unroll
            for (int ks = 0; ks < KS; ++ks) s += hp[(size_t)ks * NN * HGCN + e];
            astore(&h0[e], s);
        }
    }
    gbar(cntrel, 0);

    // ---- phase S: h32 = adj @ h0 (full wave per row, 2-half neighbor split)
    {
        int row = b + 256 * wave;
        if (row < NN) {
            int f = lane & 31, half = lane >> 5;
            int d = deg[row];
            const unsigned short* nb = nbr + (size_t)row * NBS;
            float acc = 0.f;
            int it = half;
            for (; it + 16 <= d; it += 16) {       // 8-deep per half
                float v[8];
                #pragma unroll
                for (int j = 0; j < 8; ++j) v[j] = h0[(int)nb[it + 2 * j] * HGCN + f];
                #pragma unroll
                for (int j = 0; j < 8; ++j) acc += v[j];
            }
            for (; it < d; it += 2) acc += h0[(int)nb[it] * HGCN + f];
            acc += __shfl_xor(acc, 32);
            if (half == 0) astore(&h32[row * HGCN + f], acc);
        }
    }
    gbar(cntrel, 1);

    lgconv_phase<32, 20, false>(b, wave, lane, deg, nbr, sWt1, sWb1,
                                g1, b1, m1, v1, h32, nullptr, Wout, c1,
                                T[wave], C1s[wave]);
    gbar(cntrel, 2);

    lgconv_phase<40, 24, true>(b, wave, lane, deg, nbr, sWt2, sWb2,
                               g2, b2, m2, v2, h32, c1, Wout, zbuf,
                               T[wave], C1s[wave]);
    gbar(cntrel, 3);

    // ---- phase F: out[row] = mask ? sum_{n in nbr(row)} z[n] : 0
    {
        int row = b + 256 * wave;
        if (row < NN) {
            int d = deg[row];
            const unsigned short* nb = nbr + (size_t)row * NBS;
            int ng = lane >> 3, c = lane & 7;
            float acc = 0.f;
            for (int it = ng; it < d; it += 8)
                acc += zbuf[(int)nb[it] * 8 + c];
            acc += __shfl_xor(acc, 8);
            acc += __shfl_xor(acc, 16);
            acc += __shfl_xor(acc, 32);
            if (lane < 7) {
                int fl = *flag;
                bool mk;
                if (fl == 2)      mk = ((const float*)mask)[row] != 0.0f;
                else if (fl == 1) mk = ((const unsigned char*)mask)[row] != 0;
                else              mk = ((const int*)mask)[row] != 0;
                out[row * 7 + lane] = mk ? acc : 0.0f;
            }
        }
    }
}

extern "C" void kernel_launch(void* const* d_in, const int* in_sizes, int n_in,
                              void* d_out, int out_size, void* d_ws, size_t ws_size,
                              hipStream_t stream) {
    const float* x    = (const float*)d_in[0];
    const float* adj  = (const float*)d_in[1];
    const float* W0   = (const float*)d_in[2];
    const float* W1a  = (const float*)d_in[3];
    const float* W1b  = (const float*)d_in[4];
    const float* W2a  = (const float*)d_in[5];
    const float* W2b  = (const float*)d_in[6];
    const float* Wout = (const float*)d_in[7];
    const float* g1 = (const float*)d_in[8];
    const float* b1 = (const float*)d_in[9];
    const float* m1 = (const float*)d_in[10];
    const float* v1 = (const float*)d_in[11];
    const float* g2 = (const float*)d_in[12];
    const float* b2 = (const float*)d_in[13];
    const float* m2 = (const float*)d_in[14];
    const float* v2 = (const float*)d_in[15];
    const void*  mask = d_in[16];

    char* ws = (char*)d_ws;
    int*            cntrel = (int*)(ws + 0);        // 2048 ints, zeroed by k1
    int*            flag   = (int*)(ws + 8192);     // 512 B reserved
    int*            deg    = (int*)(ws + 8704);     // 6400 B
    unsigned short* nbr    = (unsigned short*)(ws + 16384);   // 307200 B
    float*          h0     = (float*)(ws + 323584); // 204800 B
    float*          h32    = (float*)(ws + 528384); // 204800 B
    float*          c1     = (float*)(ws + 733184); // 51200 B
    float*          zbuf   = (float*)(ws + 784384); // 51200 B
    float*          wsT1   = (float*)(ws + 835584); // 12800 B
    float*          wsT2   = (float*)(ws + 848384); // 19200 B
    float*          hp     = (float*)(ws + 868352); // 16*204800 = 3.3 MB

    float* out = (float*)d_out;

    k1<<<K1B, 256, 0, stream>>>(x, W0, adj, W1a, W2a, deg, nbr,
                                (const unsigned char*)mask, flag,
                                wsT1, wsT2, cntrel, hp);
    k2<<<GB, NT, 0, stream>>>(deg, nbr, hp, h0, h32, c1, zbuf, wsT1, wsT2,
                              W1b, g1, b1, m1, v1,
                              W2b, g2, b2, m2, v2,
                              Wout, mask, flag, cntrel, out);
}